// Round 11
// baseline (2917.706 us; speedup 1.0000x reference)
//
#include <hip/hip_runtime.h>
#include <math.h>

using f16x8 = __attribute__((ext_vector_type(8))) _Float16;
using f32x4 = __attribute__((ext_vector_type(4))) float;
using u32x4 = __attribute__((ext_vector_type(4))) unsigned int;
using u16   = unsigned short;

// ---------------- problem constants ----------------
constexpr int Tst = 60;

// ---------------- workspace: A-fragment streams (layout identical to rounds 4-10) ----
constexpr int FR      = 512;
constexpr int N_AG0   = 64 * 9  * 2 * FR;
constexpr int N_AL0   = 64 * 9  * 2 * FR;
constexpr int N_AL1   = 64 * 17 * 2 * FR;
constexpr int N_AH1   = 4  * 9  * 2 * FR;
constexpr int OFF_AG0 = 0;
constexpr int OFF_AL0 = OFF_AG0 + N_AG0;
constexpr int OFF_AL1 = OFF_AL0 + N_AL0;
constexpr int OFF_AH1 = OFF_AL1 + N_AL1;
constexpr int WS_U16  = OFF_AH1 + N_AH1;          // 2,330,624 u16

// ---------------- h-exchange slabs (16-row blocks) + padded flags ----------------
// H[bc 128][par 2][layer 2] slab of [kt 8][sb 2][512] u16 = 16 KB
constexpr int N_HSLAB = 8 * 2 * 512;              // 8192 u16
constexpr int OFF_H   = WS_U16;
constexpr int N_H     = 128 * 2 * 2 * N_HSLAB;    // 4,194,304 u16
constexpr int OFF_FLG = OFF_H + N_H;
constexpr int FLG_STRIDE = 32;                    // ints (128 B line per flag)
constexpr int N_FLAGS_I  = 128 * 2 * 2 * FLG_STRIDE;
constexpr size_t WS_BYTES = (size_t)OFF_FLG * 2 + (size_t)N_FLAGS_I * sizeof(int);

__device__ __forceinline__ u16 hbits(_Float16 h) {
    union { _Float16 h; u16 u; } x; x.h = h; return x.u;
}

// ---------------- weight repack (verbatim — validated rounds 4-10) ----------------
__global__ void prep_kernel(const float* __restrict__ Wih0, const float* __restrict__ Whh0,
                            const float* __restrict__ bih0, const float* __restrict__ bhh0,
                            const float* __restrict__ Wih1, const float* __restrict__ Whh1,
                            const float* __restrict__ bih1, const float* __restrict__ bhh1,
                            const float* __restrict__ Wout1, const float* __restrict__ bout1,
                            u16* __restrict__ ws) {
    int i = blockIdx.x * 256 + threadIdx.x;
    if (i >= WS_U16) return;
    int arr, idx = i, KT;
    if (i < OFF_AL0)      { arr = 0; KT = 9; }
    else if (i < OFF_AL1) { arr = 1; idx -= OFF_AL0; KT = 9; }
    else if (i < OFF_AH1) { arr = 2; idx -= OFF_AL1; KT = 17; }
    else                  { arr = 3; idx -= OFF_AH1; KT = 9; }
    const int per_mt = KT * 2 * FR;
    const int mt = idx / per_mt;
    int r = idx - mt * per_mt;
    const int kt = r / (2 * FR);
    r -= kt * 2 * FR;
    const int s    = r >> 9;
    const int f    = r & 511;
    const int lane = f >> 3, j = f & 7;
    const int m    = mt * 16 + (lane & 15);
    const int k_in = ((lane >> 4) << 3) + j;

    float v = 0.f;
    if (arr == 3) {
        if (kt < 8) v = Wout1[m * 256 + kt * 32 + k_in];
        else if (k_in == 0) v = bout1[m];
    } else {
        const int unit = m >> 2, gate = m & 3, row = gate * 256 + unit;
        if (arr == 0) {
            if (kt < 8) v = Wih0[row * 258 + 2 + kt * 32 + k_in];
            else if (k_in == 0) v = bih0[row] + bhh0[row];
        } else if (arr == 1) {
            if (kt < 8) v = Whh0[row * 256 + kt * 32 + k_in];
            else if (k_in < 2) v = Wih0[row * 258 + k_in];
        } else {
            if (kt < 8)         v = Wih1[row * 256 + kt * 32 + k_in];
            else if (kt < 16)   v = Whh1[row * 256 + (kt - 8) * 32 + k_in];
            else if (k_in == 0) v = bih1[row] + bhh1[row];
        }
    }
    _Float16 hi = (_Float16)v;
    ws[i] = (s == 0) ? hbits(hi) : hbits((_Float16)(v - (float)hi));
}

// ---------------- helpers ----------------
__device__ __forceinline__ f32x4 MF(f16x8 a, f16x8 b, f32x4 c) {
    return __builtin_amdgcn_mfma_f32_16x16x32_f16(a, b, c, 0, 0, 0);
}
__device__ __forceinline__ float sigm(float x) { return 1.f / (1.f + __expf(-x)); }
__device__ __forceinline__ float tanh_(float x) {
    float e = __expf(-2.f * fabsf(x));
    float r = (1.f - e) / (1.f + e);
    return copysignf(r, x);
}
__device__ __forceinline__ float lstm_out(f32x4 g, float& c) {
    float iv = sigm(g[0]), fv = sigm(g[1]), gv = tanh_(g[2]), ov = sigm(g[3]);
    c = fmaf(fv, c, iv * gv);
    return ov * tanh_(c);
}
__device__ __forceinline__ void waitcnt0() {
    asm volatile("s_waitcnt vmcnt(0)" ::: "memory");
}
__device__ __forceinline__ void st16_sc(u16* p, u16 v) {
    asm volatile("global_store_short %0, %1, off sc0 sc1" :: "v"(p), "v"((unsigned)v) : "memory");
}
__device__ __forceinline__ void ld4_sc(const u32x4* p, u32x4& v) {
    asm volatile("global_load_dwordx4 %0, %1, off sc0 sc1" : "=v"(v) : "v"(p));
}
__device__ __forceinline__ void st4_sc(u32x4* p, u32x4 v) {
    asm volatile("global_store_dwordx4 %0, %1, off sc0 sc1" :: "v"(p), "v"(v) : "memory");
}
// 16 KB coherent global->LDS stage; 1024 threads x 16 B
__device__ __forceinline__ void stage16k(const u16* g, u16* lds, int t) {
    const u32x4* s = (const u32x4*)g;
    u32x4 v;
    ld4_sc(s + t, v);
    waitcnt0();
    __builtin_amdgcn_sched_barrier(0);
    ((u32x4*)lds)[t] = v;
}
__device__ __forceinline__ void spin_ge(int* p, int target) {
    while (__hip_atomic_load(p, __ATOMIC_RELAXED, __HIP_MEMORY_SCOPE_AGENT) < target)
        __builtin_amdgcn_s_sleep(1);
}
__device__ __forceinline__ size_t hidx(int bc, int par, int layer) {
    return (size_t)((bc * 2 + par) * 2 + layer) * N_HSLAB;
}
__device__ __forceinline__ int* fptr(int* flags, int bc, int layer, int uc) {
    return flags + (size_t)((bc * 2 + layer) * 2 + uc) * FLG_STRIDE;
}

// ---------------- main kernel: 256 blocks = 128 bc x 2 uc, 1024 thr = 16 waves ----
// uc = bid&1 (XCD parity -> one unit-chunk per XCD, 1.78 MB L2-resident).
// Block owns 16 batch rows x 128 units. Wave w owns M-tiles {uc*32+2w, uc*32+2w+1}.
// Retained LDS: X = h1 (staged in B), Y = h2 (staged in C). Phase A pure-local.
__global__ __launch_bounds__(1024) void lstm_main(
    const float* __restrict__ env, const float* __restrict__ hist,
    const float* __restrict__ goal, const float* __restrict__ cpos,
    const float* __restrict__ Wproj, const float* __restrict__ b_proj,
    const float* __restrict__ Wout2, const float* __restrict__ b_out2,
    u16* __restrict__ wsu, float* __restrict__ out) {

    __shared__ __align__(16) unsigned char smem[50176];
    u16*   X    = (u16*)smem;                     // 16 KB (retained h1)
    u16*   Y    = (u16*)(smem + 16384);           // 16 KB (retained h2)
    u16*   hSt  = (u16*)(smem + 32768);           // 8 KB own-slice coalesce
    float* mlpL = (float*)(smem + 40960);         // [16][68] f32 = 4352 B
    float* part = (float*)(smem + 45312);         // [128] f32
    u16*   posF = (u16*)(smem + 45824);           // [sb2][512] = 2 KB
    u16*   onesF= (u16*)(smem + 47872);           // [sb2][512] = 2 KB
    float* xbuf = (float*)smem;                   // prologue overlay [386][16]
    float* ctxL = (float*)(smem + 32768);         // prologue overlay [256][16]

    const int t  = threadIdx.x;
    const int w  = t >> 6;                        // 0..15
    const int l  = t & 63;
    const int bc = (int)blockIdx.x >> 1;          // 0..127
    const int uc = (int)blockIdx.x & 1;           // XCD parity
    const int row0 = bc * 16;

    u16* Hb = wsu + OFF_H;
    int* flags = (int*)(wsu + OFF_FLG);

    const u16* AG0w = wsu + OFF_AG0 + (size_t)(uc * 32 + 2 * w) * (9 * 1024)  + l * 8;
    const u16* A0w  = wsu + OFF_AL0 + (size_t)(uc * 32 + 2 * w) * (9 * 1024)  + l * 8;
    const u16* A1w  = wsu + OFF_AL1 + (size_t)(uc * 32 + 2 * w) * (17 * 1024) + l * 8;
    const u16* AHw  = wsu + OFF_AH1 + (size_t)w * (9 * 1024) + l * 8;   // valid for w<4

    // ---- P1: stage ctx_in [k][r] (16 rows) ----
    for (int idx = t; idx < 386 * 16; idx += 1024) {
        int r = idx & 15, k = idx >> 4;
        int gr = row0 + r; float v;
        if (k < 256)      v = env[gr * 256 + k];
        else if (k < 384) v = hist[gr * 128 + (k - 256)];
        else              v = goal[gr * 2 + (k - 384)];
        xbuf[k * 16 + r] = v;
    }
    __syncthreads();

    // ---- P2: context fp32 (256 units x 16 rows; thread = (u, 4-row chunk)) ----
    {
        const int u = t & 255, rh = t >> 8;       // rh 0..3
        float acc[4];
        float bp = b_proj[u];
#pragma unroll
        for (int rr = 0; rr < 4; ++rr) acc[rr] = bp;
        for (int k = 0; k < 386; ++k) {
            float wv = Wproj[u * 386 + k];
            const float* xr = &xbuf[k * 16 + rh * 4];
#pragma unroll
            for (int rr = 0; rr < 4; ++rr) acc[rr] = fmaf(xr[rr], wv, acc[rr]);
        }
#pragma unroll
        for (int rr = 0; rr < 4; ++rr) ctxL[u * 16 + rh * 4 + rr] = acc[rr];
    }
    __syncthreads();

    // ---- P3: write own uc-slice of h1(-1), h2(-1) slabs (parity 1) ----
    for (int idx = t; idx < 8192; idx += 1024) {
        int f = idx & 511, sb = (idx >> 9) & 1, kl = (idx >> 10) & 3;
        int layer = idx >> 12;
        int lane = f >> 3, j = f & 7;
        int k_in = ((lane >> 4) << 3) + j;
        int Ug = uc * 128 + kl * 32 + k_in;
        float v = ctxL[Ug * 16 + (lane & 15)];
        _Float16 hi = (_Float16)v;
        u16 val = sb ? hbits((_Float16)(v - (float)hi)) : hbits(hi);
        int kt = uc * 4 + kl;
        st16_sc(Hb + hidx(bc, 1, layer) + (kt * 2 + sb) * 512 + f, val);
    }
    waitcnt0();
    __syncthreads();
    if (t == 0) {
        __hip_atomic_store(fptr(flags, bc, 0, uc), 0, __ATOMIC_RELAXED, __HIP_MEMORY_SCOPE_AGENT);
        __hip_atomic_store(fptr(flags, bc, 1, uc), 0, __ATOMIC_RELAXED, __HIP_MEMORY_SCOPE_AGENT);
    }
    __syncthreads();   // ctxL reads done -> overlay region reusable

    // ---- P4: posF + onesF ----
    if (t < 1024) {
        int f = t & 511, sb = t >> 9;
        int lane = f >> 3, j = f & 7;
        int k_in = ((lane >> 4) << 3) + j;
        u16 pval = 0;
        if (k_in < 2) {
            float pv = cpos[(row0 + (lane & 15)) * 2 + k_in];
            _Float16 hi = (_Float16)pv;
            pval = sb ? hbits((_Float16)(pv - (float)hi)) : hbits(hi);
        }
        posF[sb * 512 + f] = pval;
        onesF[sb * 512 + f] = (sb == 0 && k_in == 0) ? hbits((_Float16)1.0f) : (u16)0;
    }
    __syncthreads();

    // ---- P5: stage X = h1(-1), Y = h2(-1); G0c via MFMA ----
    if (t < 2)      spin_ge(fptr(flags, bc, 0, t), 0);
    else if (t < 4) spin_ge(fptr(flags, bc, 1, t - 2), 0);
    __syncthreads();
    stage16k(Hb + hidx(bc, 1, 0), X, t);
    stage16k(Hb + hidx(bc, 1, 1), Y, t);
    __syncthreads();

    f32x4 G0c[2] = {{0,0,0,0}, {0,0,0,0}};
#pragma unroll
    for (int kt = 0; kt < 8; ++kt) {
        f16x8 bh = *(const f16x8*)&X[(kt * 2 + 0) * 512 + l * 8];
        f16x8 bl = *(const f16x8*)&X[(kt * 2 + 1) * 512 + l * 8];
#pragma unroll
        for (int mm = 0; mm < 2; ++mm) {
            const u16* p = AG0w + (mm * 9 + kt) * 1024;
            f16x8 ah = *(const f16x8*)p, al = *(const f16x8*)(p + 512);
            G0c[mm] = MF(ah, bh, G0c[mm]); G0c[mm] = MF(ah, bl, G0c[mm]); G0c[mm] = MF(al, bh, G0c[mm]);
        }
    }
    {
        f16x8 bh = *(const f16x8*)&onesF[l * 8];
        f16x8 bl = *(const f16x8*)&onesF[512 + l * 8];
#pragma unroll
        for (int mm = 0; mm < 2; ++mm) {
            const u16* p = AG0w + (mm * 9 + 8) * 1024;
            f16x8 ah = *(const f16x8*)p, al = *(const f16x8*)(p + 512);
            G0c[mm] = MF(ah, bh, G0c[mm]); G0c[mm] = MF(ah, bl, G0c[mm]); G0c[mm] = MF(al, bh, G0c[mm]);
        }
    }
    float c1[2] = {0, 0}, c2[2] = {0, 0};

    // ================= time loop =================
    for (int s = 0; s < Tst; ++s) {
        const int par = s & 1;

        // ===== Phase A (pure local): L0 from retained X + posF -> h1(s) =====
        {
            f32x4 a[2] = {G0c[0], G0c[1]};
#pragma unroll
            for (int kt = 0; kt < 8; ++kt) {
                f16x8 bh = *(const f16x8*)&X[(kt * 2 + 0) * 512 + l * 8];
                f16x8 bl = *(const f16x8*)&X[(kt * 2 + 1) * 512 + l * 8];
#pragma unroll
                for (int mm = 0; mm < 2; ++mm) {
                    const u16* p = A0w + (mm * 9 + kt) * 1024;
                    f16x8 ah = *(const f16x8*)p, al = *(const f16x8*)(p + 512);
                    a[mm] = MF(ah, bh, a[mm]); a[mm] = MF(ah, bl, a[mm]); a[mm] = MF(al, bh, a[mm]);
                }
            }
            {   // pos column (kt 8)
                f16x8 bh = *(const f16x8*)&posF[l * 8];
                f16x8 bl = *(const f16x8*)&posF[512 + l * 8];
#pragma unroll
                for (int mm = 0; mm < 2; ++mm) {
                    const u16* p = A0w + (mm * 9 + 8) * 1024;
                    f16x8 ah = *(const f16x8*)p, al = *(const f16x8*)(p + 512);
                    a[mm] = MF(ah, bh, a[mm]); a[mm] = MF(ah, bl, a[mm]); a[mm] = MF(al, bh, a[mm]);
                }
            }
#pragma unroll
            for (int mm = 0; mm < 2; ++mm) {
                float h1n = lstm_out(a[mm], c1[mm]);
                const int U = (2 * w + mm) * 4 + (l >> 4);
                const int ktl = U >> 5, ki = U & 31;
                const int f = ((l & 15) + 16 * (ki >> 3)) * 8 + (ki & 7);
                _Float16 hi = (_Float16)h1n;
                hSt[(ktl * 2 + 0) * 512 + f] = hbits(hi);
                hSt[(ktl * 2 + 1) * 512 + f] = hbits((_Float16)(h1n - (float)hi));
            }
        }
        __syncthreads();                                  // hSt ready; X reads done
        if (t < 512)
            st4_sc((u32x4*)(Hb + hidx(bc, par, 0) + uc * 4096) + t, ((const u32x4*)hSt)[t]);
        waitcnt0();
        __syncthreads();                                  // slice stored
        if (t == 0) __hip_atomic_store(fptr(flags, bc, 0, uc), s + 1,
                                       __ATOMIC_RELAXED, __HIP_MEMORY_SCOPE_AGENT);

        // ===== Phase B: Y-part first (retained, no deps); spin; stage X=h1(s); X-part =====
        {
            f32x4 a[2] = {{0,0,0,0}, {0,0,0,0}};
#pragma unroll
            for (int ks = 0; ks < 8; ++ks) {              // Whh1 @ h2(s-1), retained Y
                f16x8 bh = *(const f16x8*)&Y[(ks * 2 + 0) * 512 + l * 8];
                f16x8 bl = *(const f16x8*)&Y[(ks * 2 + 1) * 512 + l * 8];
#pragma unroll
                for (int mm = 0; mm < 2; ++mm) {
                    const u16* p = A1w + (mm * 17 + 8 + ks) * 1024;
                    f16x8 ah = *(const f16x8*)p, al = *(const f16x8*)(p + 512);
                    a[mm] = MF(ah, bh, a[mm]); a[mm] = MF(ah, bl, a[mm]); a[mm] = MF(al, bh, a[mm]);
                }
            }
            {   // bias column (kt 16)
                f16x8 bh = *(const f16x8*)&onesF[l * 8];
                f16x8 bl = *(const f16x8*)&onesF[512 + l * 8];
#pragma unroll
                for (int mm = 0; mm < 2; ++mm) {
                    const u16* p = A1w + (mm * 17 + 16) * 1024;
                    f16x8 ah = *(const f16x8*)p, al = *(const f16x8*)(p + 512);
                    a[mm] = MF(ah, bh, a[mm]); a[mm] = MF(ah, bl, a[mm]); a[mm] = MF(al, bh, a[mm]);
                }
            }
            if (t < 2) spin_ge(fptr(flags, bc, 0, t), s + 1);   // h1(s) full
            __syncthreads();
            stage16k(Hb + hidx(bc, par, 0), X, t);        // X <- h1(s), retained for A(s+1)
            __syncthreads();
#pragma unroll
            for (int kt = 0; kt < 8; ++kt) {              // Wih1 @ h1(s)
                f16x8 bh = *(const f16x8*)&X[(kt * 2 + 0) * 512 + l * 8];
                f16x8 bl = *(const f16x8*)&X[(kt * 2 + 1) * 512 + l * 8];
#pragma unroll
                for (int mm = 0; mm < 2; ++mm) {
                    const u16* p = A1w + (mm * 17 + kt) * 1024;
                    f16x8 ah = *(const f16x8*)p, al = *(const f16x8*)(p + 512);
                    a[mm] = MF(ah, bh, a[mm]); a[mm] = MF(ah, bl, a[mm]); a[mm] = MF(al, bh, a[mm]);
                }
            }
#pragma unroll
            for (int mm = 0; mm < 2; ++mm) {
                float h2n = lstm_out(a[mm], c2[mm]);
                const int U = (2 * w + mm) * 4 + (l >> 4);
                const int ktl = U >> 5, ki = U & 31;
                const int f = ((l & 15) + 16 * (ki >> 3)) * 8 + (ki & 7);
                _Float16 hi = (_Float16)h2n;
                hSt[(ktl * 2 + 0) * 512 + f] = hbits(hi);
                hSt[(ktl * 2 + 1) * 512 + f] = hbits((_Float16)(h2n - (float)hi));
            }
        }
        __syncthreads();                                  // hSt ready
        if (t < 512)
            st4_sc((u32x4*)(Hb + hidx(bc, par, 1) + uc * 4096) + t, ((const u32x4*)hSt)[t]);
        waitcnt0();
        __syncthreads();                                  // slice stored
        if (t == 0) __hip_atomic_store(fptr(flags, bc, 1, uc), s + 1,
                                       __ATOMIC_RELAXED, __HIP_MEMORY_SCOPE_AGENT);

        // ===== Phase C: stage Y = h2(s); head -> out[s], posF(s+1) =====
        if (t < 2) spin_ge(fptr(flags, bc, 1, t), s + 1);
        __syncthreads();
        stage16k(Hb + hidx(bc, par, 1), Y, t);            // Y <- h2(s), retained for B(s+1)
        __syncthreads();
        if (w < 4) {                                      // head: mlp = relu(h2@Wout1^T + b1)
            f32x4 pv = {0, 0, 0, 0};
#pragma unroll
            for (int kt = 0; kt < 8; ++kt) {
                f16x8 bh = *(const f16x8*)&Y[(kt * 2 + 0) * 512 + l * 8];
                f16x8 bl = *(const f16x8*)&Y[(kt * 2 + 1) * 512 + l * 8];
                const u16* p = AHw + kt * 1024;
                f16x8 ah = *(const f16x8*)p, al = *(const f16x8*)(p + 512);
                pv = MF(ah, bh, pv); pv = MF(ah, bl, pv); pv = MF(al, bh, pv);
            }
            {
                f16x8 bh = *(const f16x8*)&onesF[l * 8];
                f16x8 bl = *(const f16x8*)&onesF[512 + l * 8];
                const u16* p = AHw + 8 * 1024;
                f16x8 ah = *(const f16x8*)p, al = *(const f16x8*)(p + 512);
                pv = MF(ah, bh, pv); pv = MF(ah, bl, pv); pv = MF(al, bh, pv);
            }
#pragma unroll
            for (int r = 0; r < 4; ++r) pv[r] = fmaxf(pv[r], 0.f);
            *(f32x4*)&mlpL[(l & 15) * 68 + w * 16 + (l >> 4) * 4] = pv;
        }
        __syncthreads();                                  // mlpL ready
        if (t < 128) {                                    // head2 partials: (q4, r16, o2)
            const int q = t >> 5, idx = t & 31, r = idx >> 1, o = idx & 1;
            float a = 0.f;
#pragma unroll
            for (int k = 0; k < 16; ++k)
                a = fmaf(mlpL[r * 68 + q * 16 + k], Wout2[o * 64 + q * 16 + k], a);
            part[t] = a;
        }
        __syncthreads();
        if (t < 32) {
            const int r = t >> 1, o = t & 1;
            float a = b_out2[o] + part[t] + part[32 + t] + part[64 + t] + part[96 + t];
            if (uc == 0) out[((size_t)(row0 + r) * Tst + s) * 2 + o] = a;
            _Float16 hi = (_Float16)a;
            posF[r * 8 + o]       = hbits(hi);
            posF[512 + r * 8 + o] = hbits((_Float16)(a - (float)hi));
        }
        __syncthreads();                                  // posF(s+1) ready
    }
}

// ---------------- launch ----------------
extern "C" void kernel_launch(void* const* d_in, const int* in_sizes, int n_in,
                              void* d_out, int out_size, void* d_ws, size_t ws_size,
                              hipStream_t stream) {
    const float* env   = (const float*)d_in[0];
    const float* hist  = (const float*)d_in[1];
    const float* goal  = (const float*)d_in[2];
    const float* cpos  = (const float*)d_in[3];
    const float* Wproj = (const float*)d_in[4];
    const float* bproj = (const float*)d_in[5];
    const float* Wih0  = (const float*)d_in[6];
    const float* Whh0  = (const float*)d_in[7];
    const float* bih0  = (const float*)d_in[8];
    const float* bhh0  = (const float*)d_in[9];
    const float* Wih1  = (const float*)d_in[10];
    const float* Whh1  = (const float*)d_in[11];
    const float* bih1  = (const float*)d_in[12];
    const float* bhh1  = (const float*)d_in[13];
    const float* Wout1 = (const float*)d_in[14];
    const float* bout1 = (const float*)d_in[15];
    const float* Wout2 = (const float*)d_in[16];
    const float* bout2 = (const float*)d_in[17];

    if (ws_size < WS_BYTES) return;
    u16* wsu = (u16*)d_ws;

    (void)hipMemsetAsync((char*)d_ws + (size_t)OFF_FLG * 2, 0xFF,
                         (size_t)N_FLAGS_I * sizeof(int), stream);

    prep_kernel<<<(WS_U16 + 255) / 256, 256, 0, stream>>>(
        Wih0, Whh0, bih0, bhh0, Wih1, Whh1, bih1, bhh1, Wout1, bout1, wsu);

    lstm_main<<<256, 1024, 0, stream>>>(
        env, hist, goal, cpos, Wproj, bproj, Wout2, bout2, wsu, (float*)d_out);
}

// Round 12
// 2175.942 us; speedup vs baseline: 1.3409x; 1.3409x over previous
//
#include <hip/hip_runtime.h>
#include <math.h>

using f16x8 = __attribute__((ext_vector_type(8))) _Float16;
using f32x4 = __attribute__((ext_vector_type(4))) float;
using u32x4 = __attribute__((ext_vector_type(4))) unsigned int;
using u16   = unsigned short;

// ---------------- problem constants ----------------
constexpr int Tst = 60;

// ---------------- workspace: A-fragment streams (layout identical to rounds 4-11) ----
constexpr int FR      = 512;
constexpr int N_AG0   = 64 * 9  * 2 * FR;
constexpr int N_AL0   = 64 * 9  * 2 * FR;
constexpr int N_AL1   = 64 * 17 * 2 * FR;
constexpr int N_AH1   = 4  * 9  * 2 * FR;
constexpr int OFF_AG0 = 0;
constexpr int OFF_AL0 = OFF_AG0 + N_AG0;
constexpr int OFF_AL1 = OFF_AL0 + N_AL0;
constexpr int OFF_AH1 = OFF_AL1 + N_AL1;
constexpr int WS_U16  = OFF_AH1 + N_AH1;          // 2,330,624 u16

// ---------------- h-exchange slabs (16-row bc groups) + padded flags ----------------
// H[bc 128][par 2][layer 2] slab of [kt 8][sb 2][512] u16 = 16 KB
constexpr int N_HSLAB = 8 * 2 * 512;              // 8192 u16
constexpr int OFF_H   = WS_U16;
constexpr int N_H     = 128 * 2 * 2 * N_HSLAB;    // 4,194,304 u16
constexpr int OFF_FLG = OFF_H + N_H;
constexpr int FLG_STRIDE = 32;                    // ints (128 B line per flag)
constexpr int N_FLAGS_I  = 128 * 2 * 4 * FLG_STRIDE;   // 32768 ints
constexpr size_t WS_BYTES = (size_t)OFF_FLG * 2 + (size_t)N_FLAGS_I * sizeof(int);

__device__ __forceinline__ u16 hbits(_Float16 h) {
    union { _Float16 h; u16 u; } x; x.h = h; return x.u;
}

// ---------------- weight repack (verbatim — validated rounds 4-11) ----------------
__global__ void prep_kernel(const float* __restrict__ Wih0, const float* __restrict__ Whh0,
                            const float* __restrict__ bih0, const float* __restrict__ bhh0,
                            const float* __restrict__ Wih1, const float* __restrict__ Whh1,
                            const float* __restrict__ bih1, const float* __restrict__ bhh1,
                            const float* __restrict__ Wout1, const float* __restrict__ bout1,
                            u16* __restrict__ ws) {
    int i = blockIdx.x * 256 + threadIdx.x;
    if (i >= WS_U16) return;
    int arr, idx = i, KT;
    if (i < OFF_AL0)      { arr = 0; KT = 9; }
    else if (i < OFF_AL1) { arr = 1; idx -= OFF_AL0; KT = 9; }
    else if (i < OFF_AH1) { arr = 2; idx -= OFF_AL1; KT = 17; }
    else                  { arr = 3; idx -= OFF_AH1; KT = 9; }
    const int per_mt = KT * 2 * FR;
    const int mt = idx / per_mt;
    int r = idx - mt * per_mt;
    const int kt = r / (2 * FR);
    r -= kt * 2 * FR;
    const int s    = r >> 9;
    const int f    = r & 511;
    const int lane = f >> 3, j = f & 7;
    const int m    = mt * 16 + (lane & 15);
    const int k_in = ((lane >> 4) << 3) + j;

    float v = 0.f;
    if (arr == 3) {
        if (kt < 8) v = Wout1[m * 256 + kt * 32 + k_in];
        else if (k_in == 0) v = bout1[m];
    } else {
        const int unit = m >> 2, gate = m & 3, row = gate * 256 + unit;
        if (arr == 0) {
            if (kt < 8) v = Wih0[row * 258 + 2 + kt * 32 + k_in];
            else if (k_in == 0) v = bih0[row] + bhh0[row];
        } else if (arr == 1) {
            if (kt < 8) v = Whh0[row * 256 + kt * 32 + k_in];
            else if (k_in < 2) v = Wih0[row * 258 + k_in];
        } else {
            if (kt < 8)         v = Wih1[row * 256 + kt * 32 + k_in];
            else if (kt < 16)   v = Whh1[row * 256 + (kt - 8) * 32 + k_in];
            else if (k_in == 0) v = bih1[row] + bhh1[row];
        }
    }
    _Float16 hi = (_Float16)v;
    ws[i] = (s == 0) ? hbits(hi) : hbits((_Float16)(v - (float)hi));
}

// ---------------- helpers ----------------
__device__ __forceinline__ f32x4 MF(f16x8 a, f16x8 b, f32x4 c) {
    return __builtin_amdgcn_mfma_f32_16x16x32_f16(a, b, c, 0, 0, 0);
}
__device__ __forceinline__ float sigm(float x) { return 1.f / (1.f + __expf(-x)); }
__device__ __forceinline__ float tanh_(float x) {
    float e = __expf(-2.f * fabsf(x));
    float r = (1.f - e) / (1.f + e);
    return copysignf(r, x);
}
__device__ __forceinline__ float lstm_out(f32x4 g, float& c) {
    float iv = sigm(g[0]), fv = sigm(g[1]), gv = tanh_(g[2]), ov = sigm(g[3]);
    c = fmaf(fv, c, iv * gv);
    return ov * tanh_(c);
}
__device__ __forceinline__ void waitcnt0() {
    asm volatile("s_waitcnt vmcnt(0)" ::: "memory");
}
__device__ __forceinline__ void st16_sc(u16* p, u16 v) {
    asm volatile("global_store_short %0, %1, off sc0 sc1" :: "v"(p), "v"((unsigned)v) : "memory");
}
__device__ __forceinline__ void ld4_sc(const u32x4* p, u32x4& v) {
    asm volatile("global_load_dwordx4 %0, %1, off sc0 sc1" : "=v"(v) : "v"(p));
}
__device__ __forceinline__ void st4_sc(u32x4* p, u32x4 v) {
    asm volatile("global_store_dwordx4 %0, %1, off sc0 sc1" :: "v"(p), "v"(v) : "memory");
}
// 16 KB coherent global->LDS stage; 512 threads x 2 x 16 B
__device__ __forceinline__ void stage16k(const u16* g, u16* lds, int t) {
    const u32x4* s = (const u32x4*)g;
    u32x4 v0, v1;
    ld4_sc(s + t, v0); ld4_sc(s + t + 512, v1);
    waitcnt0();
    __builtin_amdgcn_sched_barrier(0);
    u32x4* d = (u32x4*)lds;
    d[t] = v0; d[t + 512] = v1;
}
__device__ __forceinline__ void spin_ge(int* p, int target) {
    while (__hip_atomic_load(p, __ATOMIC_RELAXED, __HIP_MEMORY_SCOPE_AGENT) < target)
        __builtin_amdgcn_s_sleep(1);
}
__device__ __forceinline__ size_t hidx(int bc, int par, int layer) {
    return (size_t)((bc * 2 + par) * 2 + layer) * N_HSLAB;
}
__device__ __forceinline__ int* fptr(int* flags, int bc, int layer, int uc) {
    return flags + (size_t)((bc * 2 + layer) * 4 + uc) * FLG_STRIDE;
}

// ---------------- main kernel: 512 blocks = 128 bc x 4 uc, 512 thr = 8 waves ----
// 2 blocks/CU: two independent bc sync-domains co-resident per CU — one block's
// spin/stage latency hides under the other's MFMA issue (R8 showed same-domain
// waves cannot do this).
// uc = bid&3 -> XCD&3 weight partition (1.16 MB/XCD, L2-resident — validated R5/R9).
// Block owns 16 rows x 64 units. Wave w (0..7) owns M-tiles {uc*16+2w, uc*16+2w+1}.
// Retained LDS: X = h1 (staged in B), Y = h2 (staged in C). Phase A pure-local.
__global__ __launch_bounds__(512) void lstm_main(
    const float* __restrict__ env, const float* __restrict__ hist,
    const float* __restrict__ goal, const float* __restrict__ cpos,
    const float* __restrict__ Wproj, const float* __restrict__ b_proj,
    const float* __restrict__ Wout2, const float* __restrict__ b_out2,
    u16* __restrict__ wsu, float* __restrict__ out) {

    __shared__ __align__(16) unsigned char smem[45824];
    u16*   X    = (u16*)smem;                     // 16 KB (retained h1)
    u16*   Y    = (u16*)(smem + 16384);           // 16 KB (retained h2)
    u16*   hSt  = (u16*)(smem + 32768);           // 4 KB own-slice coalesce
    float* mlpL = (float*)(smem + 36864);         // [16][68] f32 = 4352 B
    float* part = (float*)(smem + 41216);         // [128] f32
    u16*   posF = (u16*)(smem + 41728);           // [sb2][512] = 2 KB
    u16*   onesF= (u16*)(smem + 43776);           // [sb2][512] = 2 KB
    float* xbuf = (float*)smem;                   // prologue overlay [386][16] (24704 B)
    float* ctxL = (float*)(smem + 24704);         // prologue overlay [256][16] (16384 B)

    const int t  = threadIdx.x;
    const int w  = t >> 6;                        // 0..7
    const int l  = t & 63;
    const int bc = (int)blockIdx.x >> 2;          // 0..127
    const int uc = (int)blockIdx.x & 3;           // XCD&3 weight partition
    const int row0 = bc * 16;

    u16* Hb = wsu + OFF_H;
    int* flags = (int*)(wsu + OFF_FLG);

    const u16* AG0w = wsu + OFF_AG0 + (size_t)(uc * 16 + 2 * w) * (9 * 1024)  + l * 8;
    const u16* A0w  = wsu + OFF_AL0 + (size_t)(uc * 16 + 2 * w) * (9 * 1024)  + l * 8;
    const u16* A1w  = wsu + OFF_AL1 + (size_t)(uc * 16 + 2 * w) * (17 * 1024) + l * 8;
    const u16* AHw  = wsu + OFF_AH1 + (size_t)(w & 3) * (9 * 1024) + l * 8;   // used w<4

    // ---- P1: stage ctx_in [k][r] (16 rows) ----
    for (int idx = t; idx < 386 * 16; idx += 512) {
        int r = idx & 15, k = idx >> 4;
        int gr = row0 + r; float v;
        if (k < 256)      v = env[gr * 256 + k];
        else if (k < 384) v = hist[gr * 128 + (k - 256)];
        else              v = goal[gr * 2 + (k - 384)];
        xbuf[k * 16 + r] = v;
    }
    __syncthreads();

    // ---- P2: context fp32 (256 units x 16 rows; thread = (u, 8-row half)) ----
    {
        const int u = t & 255, rh = t >> 8;       // rh 0..1
        float acc[8];
        float bp = b_proj[u];
#pragma unroll
        for (int rr = 0; rr < 8; ++rr) acc[rr] = bp;
        for (int k = 0; k < 386; ++k) {
            float wv = Wproj[u * 386 + k];
            const float* xr = &xbuf[k * 16 + rh * 8];
#pragma unroll
            for (int rr = 0; rr < 8; ++rr) acc[rr] = fmaf(xr[rr], wv, acc[rr]);
        }
#pragma unroll
        for (int rr = 0; rr < 8; ++rr) ctxL[u * 16 + rh * 8 + rr] = acc[rr];
    }
    __syncthreads();

    // ---- P3: write own uc-slice of h1(-1), h2(-1) slabs (parity 1) ----
    for (int idx = t; idx < 4096; idx += 512) {
        int f = idx & 511, sb = (idx >> 9) & 1, kl = (idx >> 10) & 1;
        int layer = idx >> 11;
        int lane = f >> 3, j = f & 7;
        int k_in = ((lane >> 4) << 3) + j;
        int Ug = uc * 64 + kl * 32 + k_in;
        float v = ctxL[Ug * 16 + (lane & 15)];
        _Float16 hi = (_Float16)v;
        u16 val = sb ? hbits((_Float16)(v - (float)hi)) : hbits(hi);
        int kt = uc * 2 + kl;
        st16_sc(Hb + hidx(bc, 1, layer) + (kt * 2 + sb) * 512 + f, val);
    }
    waitcnt0();
    __syncthreads();
    if (t == 0) {
        __hip_atomic_store(fptr(flags, bc, 0, uc), 0, __ATOMIC_RELAXED, __HIP_MEMORY_SCOPE_AGENT);
        __hip_atomic_store(fptr(flags, bc, 1, uc), 0, __ATOMIC_RELAXED, __HIP_MEMORY_SCOPE_AGENT);
    }
    __syncthreads();   // ctxL reads done -> overlay region reusable

    // ---- P4: posF + onesF ----
    for (int idx = t; idx < 1024; idx += 512) {
        int f = idx & 511, sb = idx >> 9;
        int lane = f >> 3, j = f & 7;
        int k_in = ((lane >> 4) << 3) + j;
        u16 pval = 0;
        if (k_in < 2) {
            float pv = cpos[(row0 + (lane & 15)) * 2 + k_in];
            _Float16 hi = (_Float16)pv;
            pval = sb ? hbits((_Float16)(pv - (float)hi)) : hbits(hi);
        }
        posF[sb * 512 + f] = pval;
        onesF[sb * 512 + f] = (sb == 0 && k_in == 0) ? hbits((_Float16)1.0f) : (u16)0;
    }
    __syncthreads();

    // ---- P5: stage X = h1(-1), Y = h2(-1); G0c via MFMA ----
    if (t < 4)      spin_ge(fptr(flags, bc, 0, t), 0);
    else if (t < 8) spin_ge(fptr(flags, bc, 1, t - 4), 0);
    __syncthreads();
    stage16k(Hb + hidx(bc, 1, 0), X, t);
    stage16k(Hb + hidx(bc, 1, 1), Y, t);
    __syncthreads();

    f32x4 G0c[2] = {{0,0,0,0}, {0,0,0,0}};
#pragma unroll
    for (int kt = 0; kt < 8; ++kt) {
        f16x8 bh = *(const f16x8*)&X[(kt * 2 + 0) * 512 + l * 8];
        f16x8 bl = *(const f16x8*)&X[(kt * 2 + 1) * 512 + l * 8];
#pragma unroll
        for (int mm = 0; mm < 2; ++mm) {
            const u16* p = AG0w + (mm * 9 + kt) * 1024;
            f16x8 ah = *(const f16x8*)p, al = *(const f16x8*)(p + 512);
            G0c[mm] = MF(ah, bh, G0c[mm]); G0c[mm] = MF(ah, bl, G0c[mm]); G0c[mm] = MF(al, bh, G0c[mm]);
        }
    }
    {
        f16x8 bh = *(const f16x8*)&onesF[l * 8];
        f16x8 bl = *(const f16x8*)&onesF[512 + l * 8];
#pragma unroll
        for (int mm = 0; mm < 2; ++mm) {
            const u16* p = AG0w + (mm * 9 + 8) * 1024;
            f16x8 ah = *(const f16x8*)p, al = *(const f16x8*)(p + 512);
            G0c[mm] = MF(ah, bh, G0c[mm]); G0c[mm] = MF(ah, bl, G0c[mm]); G0c[mm] = MF(al, bh, G0c[mm]);
        }
    }
    float c1[2] = {0, 0}, c2[2] = {0, 0};

    // ================= time loop =================
    for (int s = 0; s < Tst; ++s) {
        const int par = s & 1;

        // ===== Phase A (pure local): L0 from retained X + posF -> h1(s) =====
        {
            f32x4 a[2] = {G0c[0], G0c[1]};
#pragma unroll
            for (int kt = 0; kt < 8; ++kt) {
                f16x8 bh = *(const f16x8*)&X[(kt * 2 + 0) * 512 + l * 8];
                f16x8 bl = *(const f16x8*)&X[(kt * 2 + 1) * 512 + l * 8];
#pragma unroll
                for (int mm = 0; mm < 2; ++mm) {
                    const u16* p = A0w + (mm * 9 + kt) * 1024;
                    f16x8 ah = *(const f16x8*)p, al = *(const f16x8*)(p + 512);
                    a[mm] = MF(ah, bh, a[mm]); a[mm] = MF(ah, bl, a[mm]); a[mm] = MF(al, bh, a[mm]);
                }
            }
            {   // pos column (kt 8)
                f16x8 bh = *(const f16x8*)&posF[l * 8];
                f16x8 bl = *(const f16x8*)&posF[512 + l * 8];
#pragma unroll
                for (int mm = 0; mm < 2; ++mm) {
                    const u16* p = A0w + (mm * 9 + 8) * 1024;
                    f16x8 ah = *(const f16x8*)p, al = *(const f16x8*)(p + 512);
                    a[mm] = MF(ah, bh, a[mm]); a[mm] = MF(ah, bl, a[mm]); a[mm] = MF(al, bh, a[mm]);
                }
            }
#pragma unroll
            for (int mm = 0; mm < 2; ++mm) {
                float h1n = lstm_out(a[mm], c1[mm]);
                const int U = (2 * w + mm) * 4 + (l >> 4);     // local unit 0..63
                const int ktl = U >> 5, ki = U & 31;
                const int f = ((l & 15) + 16 * (ki >> 3)) * 8 + (ki & 7);
                _Float16 hi = (_Float16)h1n;
                hSt[(ktl * 2 + 0) * 512 + f] = hbits(hi);
                hSt[(ktl * 2 + 1) * 512 + f] = hbits((_Float16)(h1n - (float)hi));
            }
        }
        __syncthreads();                                  // hSt ready; X reads done
        if (t < 256)
            st4_sc((u32x4*)(Hb + hidx(bc, par, 0) + uc * 2048) + t, ((const u32x4*)hSt)[t]);
        waitcnt0();
        __syncthreads();                                  // slice stored
        if (t == 0) __hip_atomic_store(fptr(flags, bc, 0, uc), s + 1,
                                       __ATOMIC_RELAXED, __HIP_MEMORY_SCOPE_AGENT);

        // ===== Phase B: Y-part first (retained, no deps); spin; stage X=h1(s); X-part =====
        {
            f32x4 a[2] = {{0,0,0,0}, {0,0,0,0}};
#pragma unroll
            for (int ks = 0; ks < 8; ++ks) {              // Whh1 @ h2(s-1), retained Y
                f16x8 bh = *(const f16x8*)&Y[(ks * 2 + 0) * 512 + l * 8];
                f16x8 bl = *(const f16x8*)&Y[(ks * 2 + 1) * 512 + l * 8];
#pragma unroll
                for (int mm = 0; mm < 2; ++mm) {
                    const u16* p = A1w + (mm * 17 + 8 + ks) * 1024;
                    f16x8 ah = *(const f16x8*)p, al = *(const f16x8*)(p + 512);
                    a[mm] = MF(ah, bh, a[mm]); a[mm] = MF(ah, bl, a[mm]); a[mm] = MF(al, bh, a[mm]);
                }
            }
            {   // bias column (kt 16)
                f16x8 bh = *(const f16x8*)&onesF[l * 8];
                f16x8 bl = *(const f16x8*)&onesF[512 + l * 8];
#pragma unroll
                for (int mm = 0; mm < 2; ++mm) {
                    const u16* p = A1w + (mm * 17 + 16) * 1024;
                    f16x8 ah = *(const f16x8*)p, al = *(const f16x8*)(p + 512);
                    a[mm] = MF(ah, bh, a[mm]); a[mm] = MF(ah, bl, a[mm]); a[mm] = MF(al, bh, a[mm]);
                }
            }
            if (t < 4) spin_ge(fptr(flags, bc, 0, t), s + 1);   // h1(s) full
            __syncthreads();
            stage16k(Hb + hidx(bc, par, 0), X, t);        // X <- h1(s), retained for A(s+1)
            __syncthreads();
#pragma unroll
            for (int kt = 0; kt < 8; ++kt) {              // Wih1 @ h1(s)
                f16x8 bh = *(const f16x8*)&X[(kt * 2 + 0) * 512 + l * 8];
                f16x8 bl = *(const f16x8*)&X[(kt * 2 + 1) * 512 + l * 8];
#pragma unroll
                for (int mm = 0; mm < 2; ++mm) {
                    const u16* p = A1w + (mm * 17 + kt) * 1024;
                    f16x8 ah = *(const f16x8*)p, al = *(const f16x8*)(p + 512);
                    a[mm] = MF(ah, bh, a[mm]); a[mm] = MF(ah, bl, a[mm]); a[mm] = MF(al, bh, a[mm]);
                }
            }
#pragma unroll
            for (int mm = 0; mm < 2; ++mm) {
                float h2n = lstm_out(a[mm], c2[mm]);
                const int U = (2 * w + mm) * 4 + (l >> 4);
                const int ktl = U >> 5, ki = U & 31;
                const int f = ((l & 15) + 16 * (ki >> 3)) * 8 + (ki & 7);
                _Float16 hi = (_Float16)h2n;
                hSt[(ktl * 2 + 0) * 512 + f] = hbits(hi);
                hSt[(ktl * 2 + 1) * 512 + f] = hbits((_Float16)(h2n - (float)hi));
            }
        }
        __syncthreads();                                  // hSt ready
        if (t < 256)
            st4_sc((u32x4*)(Hb + hidx(bc, par, 1) + uc * 2048) + t, ((const u32x4*)hSt)[t]);
        waitcnt0();
        __syncthreads();                                  // slice stored
        if (t == 0) __hip_atomic_store(fptr(flags, bc, 1, uc), s + 1,
                                       __ATOMIC_RELAXED, __HIP_MEMORY_SCOPE_AGENT);

        // ===== Phase C: stage Y = h2(s); head -> out[s], posF(s+1) =====
        if (t < 4) spin_ge(fptr(flags, bc, 1, t), s + 1);
        __syncthreads();
        stage16k(Hb + hidx(bc, par, 1), Y, t);            // Y <- h2(s), retained for B(s+1)
        __syncthreads();
        if (w < 4) {                                      // head: mlp = relu(h2@Wout1^T + b1)
            f32x4 pv = {0, 0, 0, 0};
#pragma unroll
            for (int kt = 0; kt < 8; ++kt) {
                f16x8 bh = *(const f16x8*)&Y[(kt * 2 + 0) * 512 + l * 8];
                f16x8 bl = *(const f16x8*)&Y[(kt * 2 + 1) * 512 + l * 8];
                const u16* p = AHw + kt * 1024;
                f16x8 ah = *(const f16x8*)p, al = *(const f16x8*)(p + 512);
                pv = MF(ah, bh, pv); pv = MF(ah, bl, pv); pv = MF(al, bh, pv);
            }
            {
                f16x8 bh = *(const f16x8*)&onesF[l * 8];
                f16x8 bl = *(const f16x8*)&onesF[512 + l * 8];
                const u16* p = AHw + 8 * 1024;
                f16x8 ah = *(const f16x8*)p, al = *(const f16x8*)(p + 512);
                pv = MF(ah, bh, pv); pv = MF(ah, bl, pv); pv = MF(al, bh, pv);
            }
#pragma unroll
            for (int r = 0; r < 4; ++r) pv[r] = fmaxf(pv[r], 0.f);
            *(f32x4*)&mlpL[(l & 15) * 68 + w * 16 + (l >> 4) * 4] = pv;
        }
        __syncthreads();                                  // mlpL ready
        if (t < 128) {                                    // head2 partials: (q4, r16, o2)
            const int q = t >> 5, idx = t & 31, r = idx >> 1, o = idx & 1;
            float a = 0.f;
#pragma unroll
            for (int k = 0; k < 16; ++k)
                a = fmaf(mlpL[r * 68 + q * 16 + k], Wout2[o * 64 + q * 16 + k], a);
            part[t] = a;
        }
        __syncthreads();
        if (t < 32) {
            const int r = t >> 1, o = t & 1;
            float a = b_out2[o] + part[t] + part[32 + t] + part[64 + t] + part[96 + t];
            if (uc == 0) out[((size_t)(row0 + r) * Tst + s) * 2 + o] = a;
            _Float16 hi = (_Float16)a;
            posF[r * 8 + o]       = hbits(hi);
            posF[512 + r * 8 + o] = hbits((_Float16)(a - (float)hi));
        }
        __syncthreads();                                  // posF(s+1) ready
    }
}

// ---------------- launch ----------------
extern "C" void kernel_launch(void* const* d_in, const int* in_sizes, int n_in,
                              void* d_out, int out_size, void* d_ws, size_t ws_size,
                              hipStream_t stream) {
    const float* env   = (const float*)d_in[0];
    const float* hist  = (const float*)d_in[1];
    const float* goal  = (const float*)d_in[2];
    const float* cpos  = (const float*)d_in[3];
    const float* Wproj = (const float*)d_in[4];
    const float* bproj = (const float*)d_in[5];
    const float* Wih0  = (const float*)d_in[6];
    const float* Whh0  = (const float*)d_in[7];
    const float* bih0  = (const float*)d_in[8];
    const float* bhh0  = (const float*)d_in[9];
    const float* Wih1  = (const float*)d_in[10];
    const float* Whh1  = (const float*)d_in[11];
    const float* bih1  = (const float*)d_in[12];
    const float* bhh1  = (const float*)d_in[13];
    const float* Wout1 = (const float*)d_in[14];
    const float* bout1 = (const float*)d_in[15];
    const float* Wout2 = (const float*)d_in[16];
    const float* bout2 = (const float*)d_in[17];

    if (ws_size < WS_BYTES) return;
    u16* wsu = (u16*)d_ws;

    (void)hipMemsetAsync((char*)d_ws + (size_t)OFF_FLG * 2, 0xFF,
                         (size_t)N_FLAGS_I * sizeof(int), stream);

    prep_kernel<<<(WS_U16 + 255) / 256, 256, 0, stream>>>(
        Wih0, Whh0, bih0, bhh0, Wih1, Whh1, bih1, bhh1, Wout1, bout1, wsu);

    lstm_main<<<512, 512, 0, stream>>>(
        env, hist, goal, cpos, Wproj, bproj, Wout2, bout2, wsu, (float*)d_out);
}